// Round 10
// baseline (383.490 us; speedup 1.0000x reference)
//
#include <hip/hip_runtime.h>

#define NNODE 1000
#define D 64
#define K_TOP 20
#define NROWS 32000   // B*N = 32*1000
typedef unsigned long long ull;

// ---------------- inverse norms (f64) ----------------
__global__ void norms_kernel(const float* __restrict__ e0, const float* __restrict__ e1,
                             const float* __restrict__ e2, double* __restrict__ inv_nrm) {
    int g = blockIdx.y;
    const float* e = (g == 0) ? e0 : ((g == 1) ? e1 : e2);
    int j = blockIdx.x * 256 + threadIdx.x;
    if (j < NNODE) {
        double s = 0.0;
        #pragma unroll
        for (int k = 0; k < D; ++k) { double v = (double)e[j * D + k]; s += v * v; }
        inv_nrm[g * NNODE + j] = 1.0 / sqrt(s);
    }
}

__device__ __forceinline__ double dot16(float4 v0, float4 v1, float4 v2, float4 v3,
                                        float4 r0, float4 r1, float4 r2, float4 r3) {
    double acc = 0.0;
    acc = fma((double)v0.x, (double)r0.x, acc);
    acc = fma((double)v0.y, (double)r0.y, acc);
    acc = fma((double)v0.z, (double)r0.z, acc);
    acc = fma((double)v0.w, (double)r0.w, acc);
    acc = fma((double)v1.x, (double)r1.x, acc);
    acc = fma((double)v1.y, (double)r1.y, acc);
    acc = fma((double)v1.z, (double)r1.z, acc);
    acc = fma((double)v1.w, (double)r1.w, acc);
    acc = fma((double)v2.x, (double)r2.x, acc);
    acc = fma((double)v2.y, (double)r2.y, acc);
    acc = fma((double)v2.z, (double)r2.z, acc);
    acc = fma((double)v2.w, (double)r2.w, acc);
    acc = fma((double)v3.x, (double)r3.x, acc);
    acc = fma((double)v3.y, (double)r3.y, acc);
    acc = fma((double)v3.z, (double)r3.z, acc);
    acc = fma((double)v3.w, (double)r3.w, acc);
    return acc;
}

__device__ __forceinline__ ull packkey(double cosv, int j) {
    ull b = (ull)__double_as_longlong(cosv);
    ull k = (b >> 63) ? ~b : (b | 0x8000000000000000ULL);
    return (k & ~1023ULL) | (ull)(1023 - j);
}

// ---------------- top-20 cosine: 4 queries/block, coalesced quad-dots, rank-by-count ----------------
// Candidate rows streamed ONCE per block and dotted against 4 query rows (4x less
// L2 traffic than R9, 4 independent f64 chains per candidate). Query fragments
// hoisted into 16 named float4 regs. Fold order and pack identical to passing
// rounds -> bit-identical keys. Stage 1: chunk-64 rank-by-count per query.
// Stage 2: exact global rank over the 320 survivors per query.
__global__ void __launch_bounds__(256, 2)
topk_all_kernel(const float* __restrict__ e0, const float* __restrict__ e1,
                const float* __restrict__ e2, const double* __restrict__ inv_nrm,
                int* __restrict__ idxM, int* __restrict__ idxP,
                int* __restrict__ idxN, float* __restrict__ idxf_out) {
    int g = blockIdx.y;
    const float* emb = (g == 0) ? e0 : ((g == 1) ? e1 : e2);
    int* idx_out = (g == 0) ? idxM : ((g == 1) ? idxP : idxN);
    const double* inv = inv_nrm + g * NNODE;

    int i0 = blockIdx.x * 4;       // queries i0..i0+3 (grid.x = 250)
    int tid = threadIdx.x;
    int w = tid >> 6, l = tid & 63;
    int rowq = tid >> 2;           // candidate sub-row within a pass (0..63)
    int s = tid & 3;               // 16-element segment within the row

    __shared__ float srow[4][D];                    // 4 query rows
    __shared__ __align__(16) ull skey[4][1024];     // keys per query (32 KB)
    __shared__ __align__(16) ull swin[4][320];      // 16 chunk top-20 lists per query
    srow[tid >> 6][tid & 63] = emb[(i0 + (tid >> 6)) * D + (tid & 63)];
    __syncthreads();

    double ia0 = inv[i0], ia1 = inv[i0 + 1], ia2 = inv[i0 + 2], ia3 = inv[i0 + 3];

    // hoist this lane's 16-element segment of each query row into registers
    const float4* qp0 = (const float4*)srow[0] + s * 4;
    const float4* qp1 = (const float4*)srow[1] + s * 4;
    const float4* qp2 = (const float4*)srow[2] + s * 4;
    const float4* qp3 = (const float4*)srow[3] + s * 4;
    float4 A0 = qp0[0], A1 = qp0[1], A2 = qp0[2], A3 = qp0[3];
    float4 B0 = qp1[0], B1 = qp1[1], B2 = qp1[2], B3 = qp1[3];
    float4 C0 = qp2[0], C1 = qp2[1], C2 = qp2[2], C3 = qp2[3];
    float4 E0 = qp3[0], E1 = qp3[1], E2 = qp3[2], E3 = qp3[3];

    // dot phase: 16 coalesced passes; candidate loaded once, used for 4 queries
    for (int p = 0; p < 16; ++p) {
        int j = p * 64 + rowq;
        int jc = (j < NNODE) ? j : 0;
        const float4* ej = (const float4*)(emb + (size_t)jc * D) + s * 4;
        float4 v0 = ej[0], v1 = ej[1], v2 = ej[2], v3 = ej[3];
        double a0 = dot16(v0, v1, v2, v3, A0, A1, A2, A3);
        double a1 = dot16(v0, v1, v2, v3, B0, B1, B2, B3);
        double a2 = dot16(v0, v1, v2, v3, C0, C1, C2, C3);
        double a3 = dot16(v0, v1, v2, v3, E0, E1, E2, E3);
        a0 += __shfl_xor(a0, 1, 64);  a0 += __shfl_xor(a0, 2, 64);
        a1 += __shfl_xor(a1, 1, 64);  a1 += __shfl_xor(a1, 2, 64);
        a2 += __shfl_xor(a2, 1, 64);  a2 += __shfl_xor(a2, 2, 64);
        a3 += __shfl_xor(a3, 1, 64);  a3 += __shfl_xor(a3, 2, 64);
        if (s == 0) {
            double invj = inv[jc];
            bool ok = (j < NNODE);
            skey[0][j] = ok ? packkey(a0 * ia0 * invj, j) : 0ULL;
            skey[1][j] = ok ? packkey(a1 * ia1 * invj, j) : 0ULL;
            skey[2][j] = ok ? packkey(a2 * ia2 * invj, j) : 0ULL;
            skey[3][j] = ok ? packkey(a3 * ia3 * invj, j) : 0ULL;
        }
    }
    __syncthreads();

    // stage 1: per query, rank each key within its 64-key sub-chunk (named scalars)
    for (int qq = 0; qq < 4; ++qq) {
        const ull* sq = skey[qq];
        const ulonglong2* base = (const ulonglong2*)(sq + (w << 8));
        ull k0 = sq[(w << 8) + l];
        ull k1 = sq[(w << 8) + 64 + l];
        ull k2 = sq[(w << 8) + 128 + l];
        ull k3 = sq[(w << 8) + 192 + l];
        int n0 = 0, n1 = 0, n2 = 0, n3 = 0;
        #pragma unroll 8
        for (int m = 0; m < 32; ++m) {
            ulonglong2 a0 = base[m];
            ulonglong2 a1 = base[32 + m];
            ulonglong2 a2 = base[64 + m];
            ulonglong2 a3 = base[96 + m];
            n0 += (a0.x > k0) ? 1 : 0;  n0 += (a0.y > k0) ? 1 : 0;
            n1 += (a1.x > k1) ? 1 : 0;  n1 += (a1.y > k1) ? 1 : 0;
            n2 += (a2.x > k2) ? 1 : 0;  n2 += (a2.y > k2) ? 1 : 0;
            n3 += (a3.x > k3) ? 1 : 0;  n3 += (a3.y > k3) ? 1 : 0;
        }
        if (n0 < K_TOP) swin[qq][((w << 2) + 0) * K_TOP + n0] = k0;
        if (n1 < K_TOP) swin[qq][((w << 2) + 1) * K_TOP + n1] = k1;
        if (n2 < K_TOP) swin[qq][((w << 2) + 2) * K_TOP + n2] = k2;
        if (n3 < K_TOP) swin[qq][((w << 2) + 3) * K_TOP + n3] = k3;
    }
    __syncthreads();

    // stage 2: per query, exact global rank of the 320 survivors (broadcast stream)
    for (int qq = 0; qq < 4; ++qq) {
        const ull* sw = swin[qq];
        const ulonglong2* sw2 = (const ulonglong2*)sw;
        int i = i0 + qq;
        {
            ull v = sw[tid];
            int rank = 0;
            #pragma unroll 8
            for (int m = 0; m < 160; ++m) {
                ulonglong2 ab = sw2[m];
                rank += (ab.x > v) ? 1 : 0;
                rank += (ab.y > v) ? 1 : 0;
            }
            if (rank < K_TOP) {
                int id = 1023 - (int)(v & 1023ULL);
                idx_out[i * K_TOP + rank] = id;
                if (g == 0) idxf_out[i * K_TOP + rank] = (float)id;
            }
        }
        if (tid < 64) {
            ull v = sw[256 + tid];
            int rank = 0;
            #pragma unroll 8
            for (int m = 0; m < 160; ++m) {
                ulonglong2 ab = sw2[m];
                rank += (ab.x > v) ? 1 : 0;
                rank += (ab.y > v) ? 1 : 0;
            }
            if (rank < K_TOP) {
                int id = 1023 - (int)(v & 1023ULL);
                idx_out[i * K_TOP + rank] = id;
                if (g == 0) idxf_out[i * K_TOP + rank] = (float)id;
            }
        }
    }
}

// ---------------- row GEMM (8 rows/block) ----------------
template <int K>
__global__ void rowgemm_kernel(const float* __restrict__ X, int ldx,
                               const float* __restrict__ W, const float* __restrict__ bias,
                               float* __restrict__ out) {
    __shared__ float Ws[K * D];
    __shared__ float xs[8][K];
    int tid = threadIdx.x;
    for (int e = tid; e < K * D; e += 256) Ws[e] = W[e];
    int base_row = blockIdx.x * 8;
    for (int e = tid; e < 8 * K; e += 256) {
        int r = e / K, k = e % K;
        xs[r][k] = X[(size_t)(base_row + r) * ldx + k];
    }
    __syncthreads();
    int lr = tid >> 6, c = tid & 63;
    #pragma unroll
    for (int rep = 0; rep < 2; ++rep) {
        int r = lr * 2 + rep;
        float acc = bias[c];
        #pragma unroll
        for (int k = 0; k < K; ++k) acc = fmaf(xs[r][k], Ws[k * D + c], acc);
        out[(size_t)(base_row + r) * D + c] = acc;
    }
}

// ---------------- fused mid: BN-apply + O=v@W_out + head GEMMs, O stays in LDS ----------------
__global__ void mid_fused_kernel(const float* __restrict__ t, const float* __restrict__ ss,
                                 const float* __restrict__ Wo, const float* __restrict__ bo,
                                 const float* __restrict__ Wp, const float* __restrict__ bp,
                                 const float* __restrict__ Wn, const float* __restrict__ bn_,
                                 float* __restrict__ outP, float* __restrict__ outN) {
    __shared__ float Wos[D * D];
    __shared__ float Wps[16 * D];
    __shared__ float Wns[48 * D];
    __shared__ float vs[8][D];
    __shared__ float os[8][D];
    int tid = threadIdx.x;
    for (int e = tid; e < D * D; e += 256) Wos[e] = Wo[e];
    for (int e = tid; e < 16 * D; e += 256) Wps[e] = Wp[e];
    for (int e = tid; e < 48 * D; e += 256) Wns[e] = Wn[e];
    int base = blockIdx.x * 8;
    for (int e = tid; e < 8 * D; e += 256) {
        int r = e >> 6, c = e & 63;
        float x = t[(size_t)(base + r) * D + c];
        vs[r][c] = fmaxf(fmaf(x, ss[c], ss[D + c]), 0.f);
    }
    __syncthreads();
    int lr = tid >> 6, c = tid & 63;
    #pragma unroll
    for (int rep = 0; rep < 2; ++rep) {
        int r = lr * 2 + rep;
        float acc = bo[c];
        #pragma unroll
        for (int k = 0; k < D; ++k) acc = fmaf(vs[r][k], Wos[k * D + c], acc);
        os[r][c] = acc;
    }
    __syncthreads();
    #pragma unroll
    for (int rep = 0; rep < 2; ++rep) {
        int r = lr * 2 + rep;
        float ap = bp[c];
        #pragma unroll
        for (int k = 0; k < 16; ++k) ap = fmaf(os[r][k], Wps[k * D + c], ap);
        float an = bn_[c];
        #pragma unroll
        for (int k = 0; k < 48; ++k) an = fmaf(os[r][16 + k], Wns[k * D + c], an);
        outP[(size_t)(base + r) * D + c] = ap;
        outN[(size_t)(base + r) * D + c] = an;
    }
}

// ---------------- GCN gather-mean-relu + inline BN partial sums (32 rows/block) ----------------
__device__ __forceinline__ void gcn_bn_body(const float* __restrict__ h, const int* __restrict__ idx,
                                            const float* __restrict__ emb, float* __restrict__ t_out,
                                            float* __restrict__ x_out,
                                            double* __restrict__ psum, double* __restrict__ psq,
                                            int blk) {
    __shared__ int nbrs[32][K_TOP];
    __shared__ double shs[4][D], shq[4][D];
    int tid = threadIdx.x;
    int c = tid & 63, rg = tid >> 6;
    int base_row = blk * 32;
    for (int e = tid; e < 32 * K_TOP; e += 256) {
        int rr = e / K_TOP, tt = e % K_TOP;
        int node = (base_row + rr) % NNODE;
        nbrs[rr][tt] = idx[node * K_TOP + tt];
    }
    __syncthreads();
    double aS = 0.0, aQ = 0.0;
    for (int k = 0; k < 8; ++k) {
        int rr = rg * 8 + k;
        int row = base_row + rr;
        int b = row / NNODE, i = row - b * NNODE;
        const float* hb = h + (size_t)b * NNODE * D;
        float sum = 0.f;
        #pragma unroll
        for (int t = 0; t < K_TOP; ++t) sum += hb[(size_t)nbrs[rr][t] * D + c];
        float y = fmaxf(sum * (1.0f / 20.0f), 0.f);
        if (x_out) x_out[(size_t)row * D + c] = y;
        float tv = y * emb[i * D + c];
        t_out[(size_t)row * D + c] = tv;
        aS += (double)tv;
        aQ += (double)tv * (double)tv;
    }
    shs[rg][c] = aS; shq[rg][c] = aQ;
    __syncthreads();
    if (rg == 0) {
        double s = (shs[0][c] + shs[1][c]) + (shs[2][c] + shs[3][c]);
        double q = (shq[0][c] + shq[1][c]) + (shq[2][c] + shq[3][c]);
        psum[(size_t)blk * D + c] = s;
        psq[(size_t)blk * D + c] = q;
    }
}

__global__ void gcn_bn_kernel(const float* __restrict__ h, const int* __restrict__ idx,
                              const float* __restrict__ emb, float* __restrict__ t_out,
                              float* __restrict__ x_out,
                              double* __restrict__ psum, double* __restrict__ psq) {
    gcn_bn_body(h, idx, emb, t_out, x_out, psum, psq, blockIdx.x);
}

__global__ void gcn_bn_dual_kernel(const float* __restrict__ hA, const int* __restrict__ idxA,
                                   const float* __restrict__ embA, float* __restrict__ tA,
                                   float* __restrict__ xA,
                                   const float* __restrict__ hB, const int* __restrict__ idxB,
                                   const float* __restrict__ embB, float* __restrict__ tB,
                                   float* __restrict__ xB,
                                   double* __restrict__ psum, double* __restrict__ psq) {
    if (blockIdx.y == 0) gcn_bn_body(hA, idxA, embA, tA, xA, psum, psq, blockIdx.x);
    else                 gcn_bn_body(hB, idxB, embB, tB, xB, psum + 1000 * D, psq + 1000 * D, blockIdx.x);
}

// ---------------- BN finalize over 1000 partials (256 threads, deterministic) ----------------
__device__ __forceinline__ void bn_final_body(const double* __restrict__ psum,
                                              const double* __restrict__ psq,
                                              const float* __restrict__ g,
                                              const float* __restrict__ beta,
                                              float* __restrict__ ss_out) {
    __shared__ double shs[4][D], shq[4][D];
    int tid = threadIdx.x;
    int c = tid & 63, part = tid >> 6;
    double s = 0.0, q = 0.0;
    for (int b2 = part; b2 < 1000; b2 += 4) { s += psum[b2 * D + c]; q += psq[b2 * D + c]; }
    shs[part][c] = s; shq[part][c] = q;
    __syncthreads();
    if (part == 0) {
        double S = (shs[0][c] + shs[1][c]) + (shs[2][c] + shs[3][c]);
        double Q = (shq[0][c] + shq[1][c]) + (shq[2][c] + shq[3][c]);
        const double n = (double)NROWS;
        double mu = S / n;
        double var = Q / n - mu * mu;
        double inv = 1.0 / sqrt(var + 1e-5);
        double sc = (double)g[c] * inv;
        ss_out[c] = (float)sc;
        ss_out[D + c] = (float)((double)beta[c] - mu * sc);
    }
}

__global__ void bn_final_kernel(const double* __restrict__ psum, const double* __restrict__ psq,
                                const float* __restrict__ g, const float* __restrict__ beta,
                                float* __restrict__ ss_out) {
    bn_final_body(psum, psq, g, beta, ss_out);
}

__global__ void bn_final_dual_kernel(const double* __restrict__ psum, const double* __restrict__ psq,
                                     const float* __restrict__ gP, const float* __restrict__ beP,
                                     const float* __restrict__ gN, const float* __restrict__ beN,
                                     float* __restrict__ ssP, float* __restrict__ ssN) {
    if (blockIdx.x == 0) bn_final_body(psum, psq, gP, beP, ssP);
    else                 bn_final_body(psum + 1000 * D, psq + 1000 * D, gN, beN, ssN);
}

// ---------------- fused heads: BN-apply + 64->1 (phy) / 64->3 (net) ----------------
__global__ void heads_kernel(const float* __restrict__ tP, const float* __restrict__ ssP,
                             const float* __restrict__ Wp, const float* __restrict__ bp,
                             float* __restrict__ outP,
                             const float* __restrict__ tN, const float* __restrict__ ssN,
                             const float* __restrict__ Wn, const float* __restrict__ bn_,
                             float* __restrict__ outN) {
    int tid = threadIdx.x;
    int lr = tid >> 6, c = tid & 63;
    int row = blockIdx.x * 4 + lr;
    if (blockIdx.y == 0) {
        float x = tP[(size_t)row * D + c];
        float bnv = fmaxf(fmaf(x, ssP[c], ssP[D + c]), 0.f);
        float p = bnv * Wp[c];
        #pragma unroll
        for (int s = 32; s > 0; s >>= 1) p += __shfl_down(p, s, 64);
        if (c == 0) outP[row] = p + bp[0];
    } else {
        float x = tN[(size_t)row * D + c];
        float bnv = fmaxf(fmaf(x, ssN[c], ssN[D + c]), 0.f);
        float p0 = bnv * Wn[c * 3 + 0];
        float p1 = bnv * Wn[c * 3 + 1];
        float p2 = bnv * Wn[c * 3 + 2];
        #pragma unroll
        for (int s = 32; s > 0; s >>= 1) {
            p0 += __shfl_down(p0, s, 64);
            p1 += __shfl_down(p1, s, 64);
            p2 += __shfl_down(p2, s, 64);
        }
        if (c == 0) {
            outN[(size_t)row * 3 + 0] = p0 + bn_[0];
            outN[(size_t)row * 3 + 1] = p1 + bn_[1];
            outN[(size_t)row * 3 + 2] = p2 + bn_[2];
        }
    }
}

extern "C" void kernel_launch(void* const* d_in, const int* in_sizes, int n_in,
                              void* d_out, int out_size, void* d_ws, size_t ws_size,
                              hipStream_t stream) {
    const float* data    = (const float*)d_in[0];
    // d_in[1..3] = edge_index arrays: unused by the reference
    const float* mul_emb = (const float*)d_in[4];
    const float* phy_emb = (const float*)d_in[5];
    const float* net_emb = (const float*)d_in[6];
    const float* W_share = (const float*)d_in[7];
    const float* b_share = (const float*)d_in[8];
    const float* W_phy   = (const float*)d_in[9];
    const float* b_phy   = (const float*)d_in[10];
    const float* W_net   = (const float*)d_in[11];
    const float* b_net   = (const float*)d_in[12];
    const float* g_mul   = (const float*)d_in[13];
    const float* be_mul  = (const float*)d_in[14];
    const float* g_phy   = (const float*)d_in[15];
    const float* be_phy  = (const float*)d_in[16];
    const float* g_net   = (const float*)d_in[17];
    const float* be_net  = (const float*)d_in[18];
    const float* W_out   = (const float*)d_in[19];
    const float* b_out   = (const float*)d_in[20];
    const float* W_pout  = (const float*)d_in[21];
    const float* b_pout  = (const float*)d_in[22];
    const float* W_nout  = (const float*)d_in[23];
    const float* b_nout  = (const float*)d_in[24];

    float* outf = (float*)d_out;
    float* out_phy  = outf;            // 32000
    float* out_net  = outf + 32000;    // 96000
    float* out_idx  = outf + 128000;   // 20000 (idx_mul as floats)
    float* out_xnet = outf + 148000;   // 2048000
    float* out_xphy = outf + 2196000;  // 2048000

    char* ws = (char*)d_ws;
    size_t off = 0;
    auto alloc = [&](size_t bytes) -> void* {
        void* p = (void*)(ws + off);
        off += bytes;
        off = (off + 255) & ~(size_t)255;
        return p;
    };
    int* idxM = (int*)alloc(20000 * 4);
    int* idxP = (int*)alloc(20000 * 4);
    int* idxN = (int*)alloc(20000 * 4);
    double* inv_nrm = (double*)alloc(3000 * 8);
    double* psum = (double*)alloc(2 * 1000 * 64 * 8);   // 2 banks of 1000 partials
    double* psq  = (double*)alloc(2 * 1000 * 64 * 8);
    float* ssM = (float*)alloc(128 * 4);
    float* ssP = (float*)alloc(128 * 4);
    float* ssN = (float*)alloc(128 * 4);
    float* A  = (float*)alloc((size_t)NROWS * D * 4);  // h_share -> h_phy
    float* Bb = (float*)alloc((size_t)NROWS * D * 4);  // t_mul   -> h_net
    float* C  = (float*)alloc((size_t)NROWS * D * 4);  // t_phy
    float* Dd = (float*)alloc((size_t)NROWS * D * 4);  // t_net

    // 1. graphs (f64 cosine, exact ranking), 4 queries per block
    norms_kernel<<<dim3(4, 3), 256, 0, stream>>>(mul_emb, phy_emb, net_emb, inv_nrm);
    topk_all_kernel<<<dim3(250, 3), 256, 0, stream>>>(mul_emb, phy_emb, net_emb, inv_nrm,
                                                      idxM, idxP, idxN, out_idx);

    // 2. mul path
    rowgemm_kernel<60><<<4000, 256, 0, stream>>>(data, 60, W_share, b_share, A);
    gcn_bn_kernel<<<1000, 256, 0, stream>>>(A, idxM, mul_emb, Bb, (float*)nullptr, psum, psq);
    bn_final_kernel<<<1, 256, 0, stream>>>(psum, psq, g_mul, be_mul, ssM);
    mid_fused_kernel<<<4000, 256, 0, stream>>>(Bb, ssM, W_out, b_out,
                                               W_phy, b_phy, W_net, b_net, A, Bb);

    // 3. phy / net heads
    gcn_bn_dual_kernel<<<dim3(1000, 2), 256, 0, stream>>>(A, idxP, phy_emb, C, out_xphy,
                                                          Bb, idxN, net_emb, Dd, out_xnet,
                                                          psum, psq);
    bn_final_dual_kernel<<<2, 256, 0, stream>>>(psum, psq, g_phy, be_phy, g_net, be_net, ssP, ssN);
    heads_kernel<<<dim3(8000, 2), 256, 0, stream>>>(C, ssP, W_pout, b_pout, out_phy,
                                                    Dd, ssN, W_nout, b_nout, out_net);
}

// Round 11
// 232.808 us; speedup vs baseline: 1.6472x; 1.6472x over previous
//
#include <hip/hip_runtime.h>

#define NNODE 1000
#define D 64
#define K_TOP 20
#define NROWS 32000   // B*N = 32*1000
typedef unsigned long long ull;

// ---------------- inverse norms (f64) ----------------
__global__ void norms_kernel(const float* __restrict__ e0, const float* __restrict__ e1,
                             const float* __restrict__ e2, double* __restrict__ inv_nrm) {
    int g = blockIdx.y;
    const float* e = (g == 0) ? e0 : ((g == 1) ? e1 : e2);
    int j = blockIdx.x * 256 + threadIdx.x;
    if (j < NNODE) {
        double s = 0.0;
        #pragma unroll
        for (int k = 0; k < D; ++k) { double v = (double)e[j * D + k]; s += v * v; }
        inv_nrm[g * NNODE + j] = 1.0 / sqrt(s);
    }
}

__device__ __forceinline__ ull packkey(double cosv, int j) {
    ull b = (ull)__double_as_longlong(cosv);
    ull k = (b >> 63) ? ~b : (b | 0x8000000000000000ULL);
    return (k & ~1023ULL) | (ull)(1023 - j);
}

// count of partner-list keys strictly greater than v (partner list = 20 u64)
__device__ __forceinline__ int cnt20(const ull* pl, ull v) {
    const ulonglong2* p2 = (const ulonglong2*)pl;
    int cnt = 0;
    #pragma unroll
    for (int m = 0; m < 10; ++m) {
        ulonglong2 ab = p2[m];
        cnt += (ab.x > v) ? 1 : 0;
        cnt += (ab.y > v) ? 1 : 0;
    }
    return cnt;
}

// ---------------- top-20 cosine: coalesced quad-dots + chunk-64 rank + tournament merge ----------------
// Dot phase (R9, verified): 4 consecutive threads per candidate row, fully
// coalesced; quad folded by 2 shfl_xor; lane s==0 packs the order-preserving
// u64 key (low 10 bits = 1023-j: value-tie -> smaller index) into LDS.
// Stage 1 (R9, verified): rank each key within its 64-key chunk -> 16 top-20
// lists (all slots filled; keys distinct). Stage 2 (new): 4-level pairwise
// tournament merge (rank in union = own pos + count-greater in partner list);
// 8x fewer compares than flat 320x320; exact and deterministic.
__global__ void __launch_bounds__(256, 2)
topk_all_kernel(const float* __restrict__ e0, const float* __restrict__ e1,
                const float* __restrict__ e2, const double* __restrict__ inv_nrm,
                int* __restrict__ idxM, int* __restrict__ idxP,
                int* __restrict__ idxN, float* __restrict__ idxf_out) {
    int g = blockIdx.y;
    const float* emb = (g == 0) ? e0 : ((g == 1) ? e1 : e2);
    int* idx_out = (g == 0) ? idxM : ((g == 1) ? idxP : idxN);
    const double* inv = inv_nrm + g * NNODE;

    int i = blockIdx.x;            // query row, grid.x = 1000
    int tid = threadIdx.x;
    int w = tid >> 6, l = tid & 63;
    int rowq = tid >> 2;           // candidate sub-row within a pass (0..63)
    int s = tid & 3;               // 16-element segment within the row

    __shared__ float srow[D];
    __shared__ __align__(16) ull skey[1024];   // packed keys (8 KB)
    __shared__ __align__(16) ull sw16[320];    // 16 lists of top-20
    __shared__ __align__(16) ull m8[160];      // 8 lists
    __shared__ __align__(16) ull m4[80];       // 4 lists
    __shared__ __align__(16) ull m2[40];       // 2 lists
    if (tid < D) srow[tid] = emb[i * D + tid];
    __syncthreads();

    double inv_i = inv[i];
    const float4* sr4 = (const float4*)srow + s * 4;

    // dot phase: 16 coalesced passes (unroll 2 for MLP; per-dot FMA order fixed)
    #pragma unroll 2
    for (int p = 0; p < 16; ++p) {
        int j = p * 64 + rowq;
        int jc = (j < NNODE) ? j : 0;
        const float4* ej = (const float4*)(emb + (size_t)jc * D) + s * 4;
        double acc = 0.0;
        #pragma unroll
        for (int q = 0; q < 4; ++q) {
            float4 v = ej[q];
            float4 r = sr4[q];
            acc = fma((double)v.x, (double)r.x, acc);
            acc = fma((double)v.y, (double)r.y, acc);
            acc = fma((double)v.z, (double)r.z, acc);
            acc = fma((double)v.w, (double)r.w, acc);
        }
        acc += __shfl_xor(acc, 1, 64);   // fold quad
        acc += __shfl_xor(acc, 2, 64);
        if (s == 0) {
            double cosv = acc * inv_i * inv[jc];
            skey[j] = (j < NNODE) ? packkey(cosv, j) : 0ULL;
        }
    }
    __syncthreads();

    // stage 1: rank each of this wave's 4 keys within their 64-key sub-chunks
    {
        const ulonglong2* base = (const ulonglong2*)(skey + (w << 8));
        ull k0 = skey[(w << 8) + l];
        ull k1 = skey[(w << 8) + 64 + l];
        ull k2 = skey[(w << 8) + 128 + l];
        ull k3 = skey[(w << 8) + 192 + l];
        int n0 = 0, n1 = 0, n2 = 0, n3 = 0;
        #pragma unroll 8
        for (int m = 0; m < 32; ++m) {
            ulonglong2 a0 = base[m];
            ulonglong2 a1 = base[32 + m];
            ulonglong2 a2 = base[64 + m];
            ulonglong2 a3 = base[96 + m];
            n0 += (a0.x > k0) ? 1 : 0;  n0 += (a0.y > k0) ? 1 : 0;
            n1 += (a1.x > k1) ? 1 : 0;  n1 += (a1.y > k1) ? 1 : 0;
            n2 += (a2.x > k2) ? 1 : 0;  n2 += (a2.y > k2) ? 1 : 0;
            n3 += (a3.x > k3) ? 1 : 0;  n3 += (a3.y > k3) ? 1 : 0;
        }
        if (n0 < K_TOP) sw16[((w << 2) + 0) * K_TOP + n0] = k0;
        if (n1 < K_TOP) sw16[((w << 2) + 1) * K_TOP + n1] = k1;
        if (n2 < K_TOP) sw16[((w << 2) + 2) * K_TOP + n2] = k2;
        if (n3 < K_TOP) sw16[((w << 2) + 3) * K_TOP + n3] = k3;
    }
    __syncthreads();

    // stage 2: tournament merge 16 -> 8 -> 4 -> 2 -> 1 (exact ranks, distinct keys)
    // level 1: 320 elements
    {
        int e = tid;
        int lw = e / K_TOP, r = e % K_TOP;
        ull v = sw16[e];
        int rank = r + cnt20(sw16 + (lw ^ 1) * K_TOP, v);
        if (rank < K_TOP) m8[(lw >> 1) * K_TOP + rank] = v;
        if (tid < 64) {
            int e2 = 256 + tid;
            int lw2 = e2 / K_TOP, r2 = e2 % K_TOP;
            ull v2 = sw16[e2];
            int rank2 = r2 + cnt20(sw16 + (lw2 ^ 1) * K_TOP, v2);
            if (rank2 < K_TOP) m8[(lw2 >> 1) * K_TOP + rank2] = v2;
        }
    }
    __syncthreads();
    // level 2: 160 elements
    if (tid < 160) {
        int lw = tid / K_TOP, r = tid % K_TOP;
        ull v = m8[tid];
        int rank = r + cnt20(m8 + (lw ^ 1) * K_TOP, v);
        if (rank < K_TOP) m4[(lw >> 1) * K_TOP + rank] = v;
    }
    __syncthreads();
    // level 3: 80 elements
    if (tid < 80) {
        int lw = tid / K_TOP, r = tid % K_TOP;
        ull v = m4[tid];
        int rank = r + cnt20(m4 + (lw ^ 1) * K_TOP, v);
        if (rank < K_TOP) m2[(lw >> 1) * K_TOP + rank] = v;
    }
    __syncthreads();
    // level 4: 40 elements -> final ordered top-20, write out
    if (tid < 40) {
        int lw = tid / K_TOP, r = tid % K_TOP;
        ull v = m2[tid];
        int rank = r + cnt20(m2 + (lw ^ 1) * K_TOP, v);
        if (rank < K_TOP) {
            int id = 1023 - (int)(v & 1023ULL);
            idx_out[i * K_TOP + rank] = id;
            if (g == 0) idxf_out[i * K_TOP + rank] = (float)id;
        }
    }
}

// ---------------- row GEMM (8 rows/block) ----------------
template <int K>
__global__ void rowgemm_kernel(const float* __restrict__ X, int ldx,
                               const float* __restrict__ W, const float* __restrict__ bias,
                               float* __restrict__ out) {
    __shared__ float Ws[K * D];
    __shared__ float xs[8][K];
    int tid = threadIdx.x;
    for (int e = tid; e < K * D; e += 256) Ws[e] = W[e];
    int base_row = blockIdx.x * 8;
    for (int e = tid; e < 8 * K; e += 256) {
        int r = e / K, k = e % K;
        xs[r][k] = X[(size_t)(base_row + r) * ldx + k];
    }
    __syncthreads();
    int lr = tid >> 6, c = tid & 63;
    #pragma unroll
    for (int rep = 0; rep < 2; ++rep) {
        int r = lr * 2 + rep;
        float acc = bias[c];
        #pragma unroll
        for (int k = 0; k < K; ++k) acc = fmaf(xs[r][k], Ws[k * D + c], acc);
        out[(size_t)(base_row + r) * D + c] = acc;
    }
}

// ---------------- fused mid: BN-apply + O=v@W_out + head GEMMs, O stays in LDS ----------------
__global__ void mid_fused_kernel(const float* __restrict__ t, const float* __restrict__ ss,
                                 const float* __restrict__ Wo, const float* __restrict__ bo,
                                 const float* __restrict__ Wp, const float* __restrict__ bp,
                                 const float* __restrict__ Wn, const float* __restrict__ bn_,
                                 float* __restrict__ outP, float* __restrict__ outN) {
    __shared__ float Wos[D * D];
    __shared__ float Wps[16 * D];
    __shared__ float Wns[48 * D];
    __shared__ float vs[8][D];
    __shared__ float os[8][D];
    int tid = threadIdx.x;
    for (int e = tid; e < D * D; e += 256) Wos[e] = Wo[e];
    for (int e = tid; e < 16 * D; e += 256) Wps[e] = Wp[e];
    for (int e = tid; e < 48 * D; e += 256) Wns[e] = Wn[e];
    int base = blockIdx.x * 8;
    for (int e = tid; e < 8 * D; e += 256) {
        int r = e >> 6, c = e & 63;
        float x = t[(size_t)(base + r) * D + c];
        vs[r][c] = fmaxf(fmaf(x, ss[c], ss[D + c]), 0.f);
    }
    __syncthreads();
    int lr = tid >> 6, c = tid & 63;
    #pragma unroll
    for (int rep = 0; rep < 2; ++rep) {
        int r = lr * 2 + rep;
        float acc = bo[c];
        #pragma unroll
        for (int k = 0; k < D; ++k) acc = fmaf(vs[r][k], Wos[k * D + c], acc);
        os[r][c] = acc;
    }
    __syncthreads();
    #pragma unroll
    for (int rep = 0; rep < 2; ++rep) {
        int r = lr * 2 + rep;
        float ap = bp[c];
        #pragma unroll
        for (int k = 0; k < 16; ++k) ap = fmaf(os[r][k], Wps[k * D + c], ap);
        float an = bn_[c];
        #pragma unroll
        for (int k = 0; k < 48; ++k) an = fmaf(os[r][16 + k], Wns[k * D + c], an);
        outP[(size_t)(base + r) * D + c] = ap;
        outN[(size_t)(base + r) * D + c] = an;
    }
}

// ---------------- GCN gather-mean-relu (+optional x output), t = y*emb ----------------
__device__ __forceinline__ void gcn_body(const float* __restrict__ h, const int* __restrict__ idx,
                                         const float* __restrict__ emb, float* __restrict__ t_out,
                                         float* __restrict__ x_out, int blk) {
    __shared__ int nbrs[4][K_TOP];
    int tid = threadIdx.x;
    int lr = tid >> 6, c = tid & 63;
    int row = blk * 4 + lr;
    int b = row / NNODE, i = row % NNODE;
    if (c < K_TOP) nbrs[lr][c] = idx[i * K_TOP + c];
    __syncthreads();
    const float* hb = h + (size_t)b * NNODE * D;
    float s = 0.f;
    #pragma unroll
    for (int t = 0; t < K_TOP; ++t) s += hb[(size_t)nbrs[lr][t] * D + c];
    float y = fmaxf(s * (1.0f / 20.0f), 0.f);
    if (x_out) x_out[(size_t)row * D + c] = y;
    t_out[(size_t)row * D + c] = y * emb[i * D + c];
}

__global__ void gcn_kernel(const float* __restrict__ h, const int* __restrict__ idx,
                           const float* __restrict__ emb, float* __restrict__ t_out,
                           float* __restrict__ x_out) {
    gcn_body(h, idx, emb, t_out, x_out, blockIdx.x);
}

__global__ void gcn_dual_kernel(const float* __restrict__ hA, const int* __restrict__ idxA,
                                const float* __restrict__ embA, float* __restrict__ tA,
                                float* __restrict__ xA,
                                const float* __restrict__ hB, const int* __restrict__ idxB,
                                const float* __restrict__ embB, float* __restrict__ tB,
                                float* __restrict__ xB) {
    if (blockIdx.y == 0) gcn_body(hA, idxA, embA, tA, xA, blockIdx.x);
    else                 gcn_body(hB, idxB, embB, tB, xB, blockIdx.x);
}

// ---------------- BN stats: per-block partial sums (f64, deterministic) ----------------
__device__ __forceinline__ void bn_partial_body(const float* __restrict__ t,
                                                double* __restrict__ psum,
                                                double* __restrict__ psq, int blk) {
    __shared__ double sh[256], sh2[256];
    int tid = threadIdx.x;
    const float* base = t + (size_t)blk * 125 * D;
    double s = 0.0, ss = 0.0;
    for (int e = tid; e < 125 * D; e += 256) {
        double v = (double)base[e];
        s += v; ss += v * v;
    }
    sh[tid] = s; sh2[tid] = ss;
    __syncthreads();
    if (tid < 128) { sh[tid] += sh[tid + 128]; sh2[tid] += sh2[tid + 128]; }
    __syncthreads();
    if (tid < 64) {
        psum[(size_t)blk * D + tid] = sh[tid] + sh[tid + 64];
        psq[(size_t)blk * D + tid] = sh2[tid] + sh2[tid + 64];
    }
}

__global__ void bn_partial_kernel(const float* __restrict__ t, double* __restrict__ psum,
                                  double* __restrict__ psq) {
    bn_partial_body(t, psum, psq, blockIdx.x);
}

__global__ void bn_partial_dual_kernel(const float* __restrict__ tA, const float* __restrict__ tB,
                                       double* __restrict__ psum, double* __restrict__ psq) {
    if (blockIdx.y == 0) bn_partial_body(tA, psum, psq, blockIdx.x);
    else                 bn_partial_body(tB, psum + 256 * D, psq + 256 * D, blockIdx.x);
}

__device__ __forceinline__ void bn_final_body(const double* __restrict__ psum,
                                              const double* __restrict__ psq,
                                              const float* __restrict__ g,
                                              const float* __restrict__ beta,
                                              float* __restrict__ ss_out) {
    int c = threadIdx.x;
    if (c < D) {
        double s = 0.0, sq = 0.0;
        for (int b2 = 0; b2 < 256; ++b2) { s += psum[b2 * D + c]; sq += psq[b2 * D + c]; }
        const double n = (double)NROWS;
        double mu = s / n;
        double var = sq / n - mu * mu;
        double inv = 1.0 / sqrt(var + 1e-5);
        double sc = (double)g[c] * inv;
        ss_out[c] = (float)sc;
        ss_out[D + c] = (float)((double)beta[c] - mu * sc);
    }
}

__global__ void bn_final_kernel(const double* __restrict__ psum, const double* __restrict__ psq,
                                const float* __restrict__ g, const float* __restrict__ beta,
                                float* __restrict__ ss_out) {
    bn_final_body(psum, psq, g, beta, ss_out);
}

__global__ void bn_final_dual_kernel(const double* __restrict__ psum, const double* __restrict__ psq,
                                     const float* __restrict__ gP, const float* __restrict__ beP,
                                     const float* __restrict__ gN, const float* __restrict__ beN,
                                     float* __restrict__ ssP, float* __restrict__ ssN) {
    if (blockIdx.x == 0) bn_final_body(psum, psq, gP, beP, ssP);
    else                 bn_final_body(psum + 256 * D, psq + 256 * D, gN, beN, ssN);
}

// ---------------- fused heads: BN-apply + 64->1 (phy) / 64->3 (net) ----------------
__global__ void heads_kernel(const float* __restrict__ tP, const float* __restrict__ ssP,
                             const float* __restrict__ Wp, const float* __restrict__ bp,
                             float* __restrict__ outP,
                             const float* __restrict__ tN, const float* __restrict__ ssN,
                             const float* __restrict__ Wn, const float* __restrict__ bn_,
                             float* __restrict__ outN) {
    int tid = threadIdx.x;
    int lr = tid >> 6, c = tid & 63;
    int row = blockIdx.x * 4 + lr;
    if (blockIdx.y == 0) {
        float x = tP[(size_t)row * D + c];
        float bnv = fmaxf(fmaf(x, ssP[c], ssP[D + c]), 0.f);
        float p = bnv * Wp[c];
        #pragma unroll
        for (int s = 32; s > 0; s >>= 1) p += __shfl_down(p, s, 64);
        if (c == 0) outP[row] = p + bp[0];
    } else {
        float x = tN[(size_t)row * D + c];
        float bnv = fmaxf(fmaf(x, ssN[c], ssN[D + c]), 0.f);
        float p0 = bnv * Wn[c * 3 + 0];
        float p1 = bnv * Wn[c * 3 + 1];
        float p2 = bnv * Wn[c * 3 + 2];
        #pragma unroll
        for (int s = 32; s > 0; s >>= 1) {
            p0 += __shfl_down(p0, s, 64);
            p1 += __shfl_down(p1, s, 64);
            p2 += __shfl_down(p2, s, 64);
        }
        if (c == 0) {
            outN[(size_t)row * 3 + 0] = p0 + bn_[0];
            outN[(size_t)row * 3 + 1] = p1 + bn_[1];
            outN[(size_t)row * 3 + 2] = p2 + bn_[2];
        }
    }
}

extern "C" void kernel_launch(void* const* d_in, const int* in_sizes, int n_in,
                              void* d_out, int out_size, void* d_ws, size_t ws_size,
                              hipStream_t stream) {
    const float* data    = (const float*)d_in[0];
    // d_in[1..3] = edge_index arrays: unused by the reference
    const float* mul_emb = (const float*)d_in[4];
    const float* phy_emb = (const float*)d_in[5];
    const float* net_emb = (const float*)d_in[6];
    const float* W_share = (const float*)d_in[7];
    const float* b_share = (const float*)d_in[8];
    const float* W_phy   = (const float*)d_in[9];
    const float* b_phy   = (const float*)d_in[10];
    const float* W_net   = (const float*)d_in[11];
    const float* b_net   = (const float*)d_in[12];
    const float* g_mul   = (const float*)d_in[13];
    const float* be_mul  = (const float*)d_in[14];
    const float* g_phy   = (const float*)d_in[15];
    const float* be_phy  = (const float*)d_in[16];
    const float* g_net   = (const float*)d_in[17];
    const float* be_net  = (const float*)d_in[18];
    const float* W_out   = (const float*)d_in[19];
    const float* b_out   = (const float*)d_in[20];
    const float* W_pout  = (const float*)d_in[21];
    const float* b_pout  = (const float*)d_in[22];
    const float* W_nout  = (const float*)d_in[23];
    const float* b_nout  = (const float*)d_in[24];

    float* outf = (float*)d_out;
    float* out_phy  = outf;            // 32000
    float* out_net  = outf + 32000;    // 96000
    float* out_idx  = outf + 128000;   // 20000 (idx_mul as floats)
    float* out_xnet = outf + 148000;   // 2048000
    float* out_xphy = outf + 2196000;  // 2048000

    char* ws = (char*)d_ws;
    size_t off = 0;
    auto alloc = [&](size_t bytes) -> void* {
        void* p = (void*)(ws + off);
        off += bytes;
        off = (off + 255) & ~(size_t)255;
        return p;
    };
    int* idxM = (int*)alloc(20000 * 4);
    int* idxP = (int*)alloc(20000 * 4);
    int* idxN = (int*)alloc(20000 * 4);
    double* inv_nrm = (double*)alloc(3000 * 8);
    double* psum = (double*)alloc(2 * 256 * 64 * 8);   // 2 banks
    double* psq  = (double*)alloc(2 * 256 * 64 * 8);
    float* ssM = (float*)alloc(128 * 4);
    float* ssP = (float*)alloc(128 * 4);
    float* ssN = (float*)alloc(128 * 4);
    float* A  = (float*)alloc((size_t)NROWS * D * 4);  // h_share -> h_phy
    float* Bb = (float*)alloc((size_t)NROWS * D * 4);  // t_mul   -> h_net
    float* C  = (float*)alloc((size_t)NROWS * D * 4);  // t_phy
    float* Dd = (float*)alloc((size_t)NROWS * D * 4);  // t_net

    // 1. graphs (f64 cosine, exact ranking)
    norms_kernel<<<dim3(4, 3), 256, 0, stream>>>(mul_emb, phy_emb, net_emb, inv_nrm);
    topk_all_kernel<<<dim3(1000, 3), 256, 0, stream>>>(mul_emb, phy_emb, net_emb, inv_nrm,
                                                       idxM, idxP, idxN, out_idx);

    // 2. mul path
    rowgemm_kernel<60><<<4000, 256, 0, stream>>>(data, 60, W_share, b_share, A);
    gcn_kernel<<<8000, 256, 0, stream>>>(A, idxM, mul_emb, Bb, (float*)nullptr);
    bn_partial_kernel<<<256, 256, 0, stream>>>(Bb, psum, psq);
    bn_final_kernel<<<1, 64, 0, stream>>>(psum, psq, g_mul, be_mul, ssM);
    mid_fused_kernel<<<4000, 256, 0, stream>>>(Bb, ssM, W_out, b_out,
                                               W_phy, b_phy, W_net, b_net, A, Bb);

    // 3. phy / net heads
    gcn_dual_kernel<<<dim3(8000, 2), 256, 0, stream>>>(A, idxP, phy_emb, C, out_xphy,
                                                       Bb, idxN, net_emb, Dd, out_xnet);
    bn_partial_dual_kernel<<<dim3(256, 2), 256, 0, stream>>>(C, Dd, psum, psq);
    bn_final_dual_kernel<<<2, 64, 0, stream>>>(psum, psq, g_phy, be_phy, g_net, be_net, ssP, ssN);
    heads_kernel<<<dim3(8000, 2), 256, 0, stream>>>(C, ssP, W_pout, b_pout, out_phy,
                                                    Dd, ssN, W_nout, b_nout, out_net);
}